// Round 13
// baseline (461.147 us; speedup 1.0000x reference)
//
#include <hip/hip_runtime.h>
#include <math.h>

// Problem constants
#define Hdim 1152
#define NHd  16
#define HDd  72
#define Bd   16
#define Sd   729
#define Ntok (Bd*Sd)      // 11664
#define BHd  (Bd*NHd)     // 256
#define SCALE_F 0.117851130197757934f  // 72^-0.5
#define LOG2E 1.44269504088896340736f

// Fragment-tile sizes
#define KFTB 8192    // bytes per (bh,kt): 8 chunks * 1024 (i8, K=64 layout)
#define VFT 10240    // ushorts per (bh,kt): 20 chunks * 512 (bf16 hi/lo interleaved)

// scalar slots in ws
#define SL_X 0
#define SL_WQ 1
#define SL_WK 2
#define SL_WV 3
#define SL_WO 4
#define SL_Q 5
#define SL_K 6
#define SL_LOGIT 8
#define SL_LMIN 9
#define SL_O 10

typedef short short8 __attribute__((ext_vector_type(8)));
typedef short short4v __attribute__((ext_vector_type(4)));
typedef float f32x4 __attribute__((ext_vector_type(4)));
typedef int int4v __attribute__((ext_vector_type(4)));

static __device__ __forceinline__ unsigned short f2bf(float f) {
  unsigned b = __float_as_uint(f);
  return (unsigned short)((b + 0x7FFFu + ((b >> 16) & 1u)) >> 16);  // RNE
}
static __device__ __forceinline__ float bf2f(unsigned short u) {
  return __uint_as_float(((unsigned)u) << 16);
}
static __device__ __forceinline__ void atomicMaxF(float* p, float v) {
  atomicMax((unsigned int*)p, __float_as_uint(v));   // v >= 0 only
}
static __device__ __forceinline__ void atomicMinF(float* p, float v) {
  atomicMin((unsigned int*)p, __float_as_uint(v));   // v > 0 only
}
static __device__ __forceinline__ float qscale(float mx, float qmax) {
  return fmaxf(mx, 1e-8f) / qmax;
}
static __device__ __forceinline__ float fexp2(float x) {
  float r; asm("v_exp_f32 %0, %1" : "=v"(r) : "v"(x)); return r;
}
static __device__ __forceinline__ float flog2(float x) {
  float r; asm("v_log_f32 %0, %1" : "=v"(r) : "v"(x)); return r;
}
static __device__ __forceinline__ short4v pack4(unsigned a, unsigned b, unsigned c, unsigned d) {
  union { unsigned u[2]; short4v s; } t;
  t.u[0] = a | (b << 16);
  t.u[1] = c | (d << 16);
  return t.s;
}
static __device__ __forceinline__ int q8i(float v, float s) {
  return (int)fminf(fmaxf(rintf(v / s), -128.f), 127.f);
}

#if __has_builtin(__builtin_amdgcn_mfma_f32_16x16x16bf16_1k)
#define MFMA16(a, b, c) __builtin_amdgcn_mfma_f32_16x16x16bf16_1k(a, b, c, 0, 0, 0)
#else
static __device__ __forceinline__ f32x4 MFMA16(short4v a, short4v b, f32x4 c) {
  asm("v_mfma_f32_16x16x16_bf16 %0, %1, %2, %0" : "+v"(c) : "v"(a), "v"(b));
  return c;
}
#endif
#if __has_builtin(__builtin_amdgcn_mfma_i32_16x16x64_i8)
#define MFMAI8(a, b, c) __builtin_amdgcn_mfma_i32_16x16x64_i8(a, b, c, 0, 0, 0)
#else
static __device__ __forceinline__ int4v MFMAI8(int4v a, int4v b, int4v c) {
  asm("v_mfma_i32_16x16x64_i8 %0, %1, %2, %0" : "+v"(c) : "v"(a), "v"(b));
  return c;
}
#endif

static __device__ __forceinline__ void gll16(const void* g, void* l) {
  __builtin_amdgcn_global_load_lds((const __attribute__((address_space(1))) void*)g,
                                   (__attribute__((address_space(3))) void*)l, 16, 0, 0);
}

// ---------------- init ----------------
__global__ void k_init(float* slots) {
  int i = threadIdx.x;
  if (i < 32) slots[i] = (i == SL_LMIN) ? __builtin_inff() : 0.0f;
}

// ---------------- abs-max over X and the 4 weights ----------------
__launch_bounds__(256)
__global__ void k_absmax(const float* __restrict__ X, const float* __restrict__ W0,
                         const float* __restrict__ W1, const float* __restrict__ W2,
                         const float* __restrict__ W3, float* slots) {
  int seg = blockIdx.y;
  const float* p; long n; int slot;
  if (seg == 0) { p = X; n = (long)Ntok * Hdim; slot = SL_X; }
  else {
    const float* ws4[4] = {W0, W1, W2, W3};
    p = ws4[seg - 1]; n = (long)Hdim * Hdim; slot = SL_WQ + seg - 1;
  }
  long n4 = n >> 2;
  const float4* p4 = (const float4*)p;
  float m = 0.f;
  for (long i = (long)blockIdx.x * blockDim.x + threadIdx.x; i < n4;
       i += (long)gridDim.x * blockDim.x) {
    float4 v = p4[i];
    m = fmaxf(m, fmaxf(fmaxf(fabsf(v.x), fabsf(v.y)), fmaxf(fabsf(v.z), fabsf(v.w))));
  }
  for (int off = 32; off; off >>= 1) m = fmaxf(m, __shfl_xor(m, off, 64));
  __shared__ float red[4];
  if ((threadIdx.x & 63) == 0) red[threadIdx.x >> 6] = m;
  __syncthreads();
  if (threadIdx.x == 0)
    atomicMaxF(&slots[slot], fmaxf(fmaxf(red[0], red[1]), fmaxf(red[2], red[3])));
}

// ---------------- 8-bit fake-quant helper body ----------------
static __device__ __forceinline__ void quant_body(const float* __restrict__ in,
                                                  unsigned int* __restrict__ out,
                                                  long n4, float s, long start, long stride) {
  const float4* in4 = (const float4*)in;
  for (long i = start; i < n4; i += stride) {
    float4 v = in4[i];
    unsigned a = (unsigned)q8i(v.x, s) & 255u;
    unsigned b = (unsigned)q8i(v.y, s) & 255u;
    unsigned c = (unsigned)q8i(v.z, s) & 255u;
    unsigned d = (unsigned)q8i(v.w, s) & 255u;
    out[i] = a | (b << 8) | (c << 16) | (d << 24);
  }
}

// f32 -> i8 (standalone, for O)
__launch_bounds__(256)
__global__ void k_quant8i(const float* __restrict__ in, unsigned int* __restrict__ out,
                          long n, const float* __restrict__ slots, int slot) {
  float s = qscale(slots[slot], 127.0f);
  quant_body(in, out, n >> 2, s,
             (long)blockIdx.x * blockDim.x + threadIdx.x,
             (long)gridDim.x * blockDim.x);
}

// fused X + 4 weights quant: grid (1024, 1, 2)
__launch_bounds__(256)
__global__ void k_quantXW(const float* __restrict__ X, const float* __restrict__ W0,
                          const float* __restrict__ W1, const float* __restrict__ W2,
                          const float* __restrict__ W3,
                          unsigned int* OX, unsigned int* O0, unsigned int* O1,
                          unsigned int* O2, unsigned int* O3,
                          const float* __restrict__ slots) {
  if (blockIdx.z == 0) {
    float s = qscale(slots[SL_X], 127.0f);
    quant_body(X, OX, ((long)Ntok * Hdim) >> 2, s,
               (long)blockIdx.x * blockDim.x + threadIdx.x,
               (long)gridDim.x * blockDim.x);
  } else {
    int seg = blockIdx.x & 3;
    const float* ws4[4] = {W0, W1, W2, W3};
    unsigned int* os4[4] = {O0, O1, O2, O3};
    float s = qscale(slots[SL_WQ + seg], 127.0f);
    quant_body(ws4[seg], os4[seg], ((long)Hdim * Hdim) >> 2, s,
               (long)(blockIdx.x >> 2) * blockDim.x + threadIdx.x,
               (long)(gridDim.x >> 2) * blockDim.x);
  }
}

// ---------------- i8 GEMM core: dbuf LDS + counted vmcnt, swizzled reads ----------------
#define GBM 128
#define GBN 128
static __device__ __forceinline__ void gemm_core(const char* __restrict__ A,
                                                 const char* __restrict__ Bm,
                                                 int bM, int bN, int tid,
                                                 char (*As)[GBM][64],
                                                 char (*Bs)[GBN][64],
                                                 int4v acc[4][4]) {
  int lane = tid & 63, wid = tid >> 6;
  int wm = wid >> 1, wn = wid & 1;
  int l15 = lane & 15, l4 = lane >> 4;
  int srow = lane >> 2;
  int scol = ((lane & 3) ^ ((lane >> 3) & 3)) * 16;   // inverse-swizzled source col
  const char* pa = A + ((long)(bM * GBM + wid * 32) + srow) * Hdim + scol;
  const char* pb = Bm + ((long)(bN * GBN + wid * 32) + srow) * Hdim + scol;
  int csw = (l4 ^ ((l15 >> 1) & 3)) * 16;             // swizzled read chunk offset

  auto stage = [&](int buf, int kt) {
    int kb = kt * 64;
    gll16(pa + kb, &As[buf][wid * 32][0]);
    gll16(pa + kb + 16 * Hdim, &As[buf][wid * 32 + 16][0]);
    gll16(pb + kb, &Bs[buf][wid * 32][0]);
    gll16(pb + kb + 16 * Hdim, &Bs[buf][wid * 32 + 16][0]);
  };

  stage(0, 0);
#pragma unroll 1
  for (int kt = 0; kt < 18; ++kt) {
    int cur = kt & 1;
    if (kt < 17) {
      stage(cur ^ 1, kt + 1);
      asm volatile("s_waitcnt vmcnt(4)" ::: "memory");  // kt's 4 glls done; kt+1's in flight
    } else {
      asm volatile("s_waitcnt vmcnt(0)" ::: "memory");
    }
    asm volatile("s_barrier" ::: "memory");
    int4v af[4], bf4[4];
#pragma unroll
    for (int rf = 0; rf < 4; ++rf)
      af[rf] = *(const int4v*)&As[cur][wm * 64 + rf * 16 + l15][csw];
#pragma unroll
    for (int cf = 0; cf < 4; ++cf)
      bf4[cf] = *(const int4v*)&Bs[cur][wn * 64 + cf * 16 + l15][csw];
#pragma unroll
    for (int rf = 0; rf < 4; ++rf)
#pragma unroll
      for (int cf = 0; cf < 4; ++cf)
        acc[rf][cf] = MFMAI8(af[rf], bf4[cf], acc[rf][cf]);
    asm volatile("s_barrier" ::: "memory");   // reads of buf[cur] done before restage
  }
}

__launch_bounds__(256, 4)
__global__ void k_gemm(const char* __restrict__ A,
                       const char* __restrict__ Bm,
                       const float* __restrict__ bias,
                       float* __restrict__ C,
                       float* slots, int slotA, int slotB, int slotOut) {
  __shared__ char As[2][GBM][64];
  __shared__ char Bs[2][GBN][64];
  __shared__ float red[4];
  int tid = threadIdx.x, lane = tid & 63, wid = tid >> 6;
  int wm = wid >> 1, wn = wid & 1;
  int l15 = lane & 15, l4 = lane >> 4;
  int bM = blockIdx.x, bN = blockIdx.y;
  int4v acc[4][4];
  for (int rf = 0; rf < 4; ++rf)
    for (int cf = 0; cf < 4; ++cf) acc[rf][cf] = int4v{0, 0, 0, 0};
  gemm_core(A, Bm, bM, bN, tid, As, Bs, acc);
  float alpha = qscale(slots[slotA], 127.f) * qscale(slots[slotB], 127.f);
  float lmax = 0.f;
#pragma unroll
  for (int cf = 0; cf < 4; ++cf) {
    int col = bN * GBN + wn * 64 + cf * 16 + l15;
    float bv = bias[col];
#pragma unroll
    for (int rf = 0; rf < 4; ++rf)
#pragma unroll
      for (int j = 0; j < 4; ++j) {
        int row = bM * GBM + wm * 64 + rf * 16 + l4 * 4 + j;
        if (row < Ntok) {
          float v = (float)acc[rf][cf][j] * alpha + bv;
          C[(long)row * Hdim + col] = v;
          lmax = fmaxf(lmax, fabsf(v));
        }
      }
  }
  if (slotOut >= 0) {
    for (int off = 32; off; off >>= 1) lmax = fmaxf(lmax, __shfl_xor(lmax, off, 64));
    if ((tid & 63) == 0) red[wid] = lmax;
    __syncthreads();
    if (tid == 0)
      atomicMaxF(&slots[slotOut], fmaxf(fmaxf(red[0], red[1]), fmaxf(red[2], red[3])));
  }
}

// ---------------- fused QKV i8 GEMM ----------------
__launch_bounds__(256, 4)
__global__ void k_gemm3(const char* __restrict__ A,
                        const char* __restrict__ W0,
                        const char* __restrict__ W1,
                        const char* __restrict__ W2,
                        const float* __restrict__ b0, const float* __restrict__ b1,
                        const float* __restrict__ b2,
                        float* __restrict__ C0, float* __restrict__ C1,
                        float* __restrict__ C2, float* slots) {
  __shared__ char As[2][GBM][64];
  __shared__ char Bs[2][GBN][64];
  __shared__ float red[4];
  int bNg = blockIdx.y;                       // 0..26
  int mi = bNg / 9, bN = bNg - mi * 9;
  const char* Bm = mi == 0 ? W0 : (mi == 1 ? W1 : W2);
  const float* bias = mi == 0 ? b0 : (mi == 1 ? b1 : b2);
  float* C = mi == 0 ? C0 : (mi == 1 ? C1 : C2);
  int slotB = SL_WQ + mi;
  int slotOut = mi == 0 ? SL_Q : (mi == 1 ? SL_K : -1);

  int tid = threadIdx.x, lane = tid & 63, wid = tid >> 6;
  int wm = wid >> 1, wn = wid & 1;
  int l15 = lane & 15, l4 = lane >> 4;
  int bM = blockIdx.x;
  int4v acc[4][4];
  for (int rf = 0; rf < 4; ++rf)
    for (int cf = 0; cf < 4; ++cf) acc[rf][cf] = int4v{0, 0, 0, 0};
  gemm_core(A, Bm, bM, bN, tid, As, Bs, acc);
  float alpha = qscale(slots[SL_X], 127.f) * qscale(slots[slotB], 127.f);
  float lmax = 0.f;
#pragma unroll
  for (int cf = 0; cf < 4; ++cf) {
    int col = bN * GBN + wn * 64 + cf * 16 + l15;
    float bv = bias[col];
#pragma unroll
    for (int rf = 0; rf < 4; ++rf)
#pragma unroll
      for (int j = 0; j < 4; ++j) {
        int row = bM * GBM + wm * 64 + rf * 16 + l4 * 4 + j;
        if (row < Ntok) {
          float v = (float)acc[rf][cf][j] * alpha + bv;
          C[(long)row * Hdim + col] = v;
          lmax = fmaxf(lmax, fabsf(v));
        }
      }
  }
  if (slotOut >= 0) {
    for (int off = 32; off; off >>= 1) lmax = fmaxf(lmax, __shfl_xor(lmax, off, 64));
    if ((tid & 63) == 0) red[wid] = lmax;
    __syncthreads();
    if (tid == 0)
      atomicMaxF(&slots[slotOut], fmaxf(fmaxf(red[0], red[1]), fmaxf(red[2], red[3])));
  }
}

// ---------------- fused prep: z=0 Q-quant, z=1 K-frag, z=2 V-split ----------------
// grid (12, 256, 3)
__launch_bounds__(256)
__global__ void k_prep(const float* __restrict__ Qf, unsigned int* __restrict__ Qq,
                       const float* __restrict__ Kf, char* __restrict__ KF,
                       const float* __restrict__ Vf, unsigned short* __restrict__ VF,
                       const float* __restrict__ slots) {
  int kt = blockIdx.x, bh = blockIdx.y;
  int b = bh >> 4, h = bh & 15;
  int tid = threadIdx.x, lane = tid & 63, w = tid >> 6;
  int l15 = lane & 15, l4 = lane >> 4;
  if (blockIdx.z == 0) {
    float s = qscale(slots[SL_Q], 127.0f);
    quant_body(Qf, Qq, ((long)Ntok * Hdim) >> 2, s,
               (long)(bh * 12 + kt) * 256 + tid, (long)12 * 256 * 256);
  } else if (blockIdx.z == 1) {
    float s = qscale(slots[SL_K], 127.0f);
    long obase = ((long)(bh * 12 + kt)) * KFTB;
#pragma unroll
    for (int i = 0; i < 2; ++i) {
      int p = w * 2 + i;
      int cf = p >> 1, c = p & 1;
      int token = kt * 64 + cf * 16 + l15;
      char ov[16];
#pragma unroll
      for (int j = 0; j < 16; ++j) ov[j] = 0;
      if (token < Sd) {
        const float* src = &Kf[((long)(b * Sd + token)) * Hdim + h * HDd];
        if (c == 0) {
#pragma unroll
          for (int j = 0; j < 16; ++j) ov[j] = (char)q8i(src[l4 * 16 + j], s);
        } else if (l4 == 0) {
#pragma unroll
          for (int j = 0; j < 8; ++j) ov[j] = (char)q8i(src[64 + j], s);
        }
      }
      *(int4v*)&KF[obase + p * 1024 + lane * 16] = *(int4v*)ov;
    }
  } else {
    long obase = ((long)(bh * 12 + kt)) * VFT;
#pragma unroll
    for (int i = 0; i < 5; ++i) {
      int p = w + 4 * i;            // p = dt*4 + cf
      int dt = p >> 2, cf = p & 3;
      int d = dt * 16 + l15;
      int tok0 = kt * 64 + cf * 16 + l4 * 4;
      unsigned short u[8];
#pragma unroll
      for (int j = 0; j < 4; ++j) {
        int tok = tok0 + j;
        float v = 0.f;
        if (tok < Sd && d < HDd)
          v = Vf[((long)(b * Sd + tok)) * Hdim + h * HDd + d];
        unsigned short hb = f2bf(v);
        u[j] = hb;
        u[4 + j] = f2bf(v - bf2f(hb));
      }
      *(short8*)&VF[obase + (long)p * 512 + lane * 8] = *(short8*)u;
    }
  }
}

// per-lane i8 Q fragments straight from global (B operand: q col = l15, K-grp = l4)
static __device__ __forceinline__ void loadQ8(const char* __restrict__ Qq,
                                              int b, int h, int qc, int l4,
                                              int4v& qa, int4v& qb) {
  const char* qp = &Qq[((long)(b * Sd + qc)) * Hdim + h * HDd];
  union { long l[2]; int4v v; } u0, u1;
  u0.l[0] = *(const long*)(qp + l4 * 16);
  u0.l[1] = *(const long*)(qp + l4 * 16 + 8);
  qa = u0.v;
  u1.l[0] = (l4 == 0) ? *(const long*)(qp + 64) : 0L;
  u1.l[1] = 0L;
  qb = u1.v;
}

// ---------------- attn pass A: global max |logit| ----------------
// grid (4, 256): 3 q-tiles per block; K frags in registers, no LDS/barriers.
__launch_bounds__(256, 4)
__global__ void k_attnA(const char* __restrict__ Qq,
                        const char* __restrict__ KF, float* slots) {
  __shared__ float red[4];
  int qh = blockIdx.x, bh = blockIdx.y;
  int b = bh >> 4, h = bh & 15;
  int tid = threadIdx.x, lane = tid & 63, w = tid >> 6;
  int l15 = lane & 15, l4 = lane >> 4;
  const char* kfb = KF + (long)bh * 12 * KFTB;
  int4v qa[3], qb[3];
#pragma unroll
  for (int qs = 0; qs < 3; ++qs) {
    int qrow = (qh * 3 + qs) * 64 + w * 16 + l15;
    int qc = qrow > Sd - 1 ? Sd - 1 : qrow;
    loadQ8(Qq, b, h, qc, l4, qa[qs], qb[qs]);
  }
  float mx = 0.f;
#pragma unroll 1
  for (int kt = 0; kt < 12; ++kt) {
    int4v kf[8];
#pragma unroll
    for (int p = 0; p < 8; ++p)
      kf[p] = *(const int4v*)&kfb[(long)kt * KFTB + p * 1024 + lane * 16];
#pragma unroll
    for (int qs = 0; qs < 3; ++qs) {
#pragma unroll
      for (int cf = 0; cf < 4; ++cf) {
        int4v a = int4v{0, 0, 0, 0};
        a = MFMAI8(kf[cf * 2 + 0], qa[qs], a);
        a = MFMAI8(kf[cf * 2 + 1], qb[qs], a);
#pragma unroll
        for (int j = 0; j < 4; ++j) mx = fmaxf(mx, fabsf((float)a[j]));
      }
    }
  }
  mx *= qscale(slots[SL_Q], 127.f) * qscale(slots[SL_K], 127.f);
  for (int off = 32; off; off >>= 1) mx = fmaxf(mx, __shfl_xor(mx, off, 64));
  if ((tid & 63) == 0) red[w] = mx;
  __syncthreads();
  if (tid == 0)
    atomicMaxF(&slots[SL_LOGIT], fmaxf(fmaxf(red[0], red[1]), fmaxf(red[2], red[3])));
}

// ---------------- attn pass B: per-row m (n-space), l ; global min l ----------------
__launch_bounds__(256, 4)
__global__ void k_attnB(const char* __restrict__ Qq,
                        const char* __restrict__ KF, float* slots,
                        float* __restrict__ m_arr, float* __restrict__ l_arr) {
  __shared__ float red[4];
  int qh = blockIdx.x, bh = blockIdx.y;
  int b = bh >> 4, h = bh & 15;
  int tid = threadIdx.x, lane = tid & 63, w = tid >> 6;
  int l15 = lane & 15, l4 = lane >> 4;
  const char* kfb = KF + (long)bh * 12 * KFTB;
  int4v qa[3], qb[3];
#pragma unroll
  for (int qs = 0; qs < 3; ++qs) {
    int qrow = (qh * 3 + qs) * 64 + w * 16 + l15;
    int qc = qrow > Sd - 1 ? Sd - 1 : qrow;
    loadQ8(Qq, b, h, qc, l4, qa[qs], qb[qs]);
  }
  float s16 = qscale(slots[SL_LOGIT], 32767.f);
  float sqk = qscale(slots[SL_Q], 127.f) * qscale(slots[SL_K], 127.f);
  float c0 = sqk / s16;                 // raw-dot -> n units
  float c1e = s16 * SCALE_F * LOG2E;    // n units -> log2 space
  float m_run[3] = {-3.0e38f, -3.0e38f, -3.0e38f};
  float l_run[3] = {0.f, 0.f, 0.f};
#pragma unroll 1
  for (int kt = 0; kt < 12; ++kt) {
    int4v kf[8];
#pragma unroll
    for (int p = 0; p < 8; ++p)
      kf[p] = *(const int4v*)&kfb[(long)kt * KFTB + p * 1024 + lane * 16];
#pragma unroll
    for (int qs = 0; qs < 3; ++qs) {
      float nv[16];
#pragma unroll
      for (int cf = 0; cf < 4; ++cf) {
        int4v a = int4v{0, 0, 0, 0};
        a = MFMAI8(kf[cf * 2 + 0], qa[qs], a);
        a = MFMAI8(kf[cf * 2 + 1], qb[qs], a);
#pragma unroll
        for (int j = 0; j < 4; ++j) nv[cf * 4 + j] = rintf((float)a[j] * c0);
      }
      if (kt == 11) {
#pragma unroll
        for (int cf = 0; cf < 4; ++cf)
#pragma unroll
          for (int j = 0; j < 4; ++j) {
            int kcol = 704 + cf * 16 + l4 * 4 + j;
            if (kcol > Sd - 1) nv[cf * 4 + j] = -3.0e30f;
          }
      }
      float mt = nv[0];
#pragma unroll
      for (int i = 1; i < 16; ++i) mt = fmaxf(mt, nv[i]);
      mt = fmaxf(mt, __shfl_xor(mt, 16, 64));
      mt = fmaxf(mt, __shfl_xor(mt, 32, 64));
      float mn = fmaxf(m_run[qs], mt);
      float f = fexp2((m_run[qs] - mn) * c1e);
      float se = 0.f;
#pragma unroll
      for (int i = 0; i < 16; ++i) se += fexp2((nv[i] - mn) * c1e);
      se += __shfl_xor(se, 16, 64);
      se += __shfl_xor(se, 32, 64);
      l_run[qs] = l_run[qs] * f + se;
      m_run[qs] = mn;
    }
  }
  float lmin = 3.0e38f;
#pragma unroll
  for (int qs = 0; qs < 3; ++qs) {
    int qrow = (qh * 3 + qs) * 64 + w * 16 + l15;
    if (qrow < Sd) {
      if (l4 == 0) {
        m_arr[bh * Sd + qrow] = m_run[qs];
        l_arr[bh * Sd + qrow] = l_run[qs];
      }
      lmin = fminf(lmin, l_run[qs]);
    }
  }
  for (int off = 32; off; off >>= 1) lmin = fminf(lmin, __shfl_xor(lmin, off, 64));
  if ((tid & 63) == 0) red[w] = lmin;
  __syncthreads();
  if (tid == 0)
    atomicMinF(&slots[SL_LMIN], fminf(fminf(red[0], red[1]), fminf(red[2], red[3])));
}

// ---------------- attn pass C: single-buf LDS staging, 3 q-tiles/block ----------------
// grid (4, 256) = 1024 blocks = exactly 4/CU: one clean round, staging amortized 3x.
__launch_bounds__(256, 4)
__global__ void k_attnC(const char* __restrict__ Qq,
                        const char* __restrict__ KF,
                        const unsigned short* __restrict__ VF,
                        const float* __restrict__ m_arr, const float* __restrict__ l_arr,
                        float* slots, float* __restrict__ O) {
  __shared__ char Ks[KFTB];
  __shared__ unsigned short Vs[VFT];
  __shared__ float red[4];
  int qp, bh;
  {
    int id = blockIdx.y * 4 + blockIdx.x;   // 0..1023
    int xcd = id & 7, sub = id >> 3;        // 128 per xcd
    int bhl = sub >> 2;                     // 0..31
    qp = sub & 3;                           // 0..3
    bh = xcd * 32 + bhl;
  }
  int b = bh >> 4, h = bh & 15;
  int tid = threadIdx.x, lane = tid & 63, w = tid >> 6;
  int l15 = lane & 15, l4 = lane >> 4;
  float s16 = qscale(slots[SL_LOGIT], 32767.f);
  float sqk = qscale(slots[SL_Q], 127.f) * qscale(slots[SL_K], 127.f);
  float c0 = sqk / s16;
  float c1e = s16 * SCALE_F * LOG2E;
  float pmaxv = 1.0f / slots[SL_LMIN];
  float sp = fmaxf(pmaxv, 1e-8f) / 32767.0f;
  float inv_sp = 1.0f / sp;
  int4v qa[3], qb[3];
  float dexp[3];      // log2(c2) - mn*c1e : folds /l, /sp, -m into the exponent
#pragma unroll
  for (int qs = 0; qs < 3; ++qs) {
    int qrow = (qp * 3 + qs) * 64 + w * 16 + l15;
    int qc = qrow > Sd - 1 ? Sd - 1 : qrow;
    loadQ8(Qq, b, h, qc, l4, qa[qs], qb[qs]);
    float mn = m_arr[bh * Sd + qc];
    float c2 = (1.0f / l_arr[bh * Sd + qc]) * inv_sp;
    dexp[qs] = flog2(c2) - mn * c1e;
  }
  const char* kfb = KF + (long)bh * 12 * KFTB;
  const unsigned short* vfb = VF + (long)bh * 12 * VFT;
  f32x4 acc[3][5];
#pragma unroll
  for (int qs = 0; qs < 3; ++qs)
#pragma unroll
    for (int i = 0; i < 5; ++i) acc[qs][i] = f32x4{0.f, 0.f, 0.f, 0.f};

#pragma unroll 1
  for (int kt = 0; kt < 12; ++kt) {
    __syncthreads();    // prior iteration's LDS reads complete
    {
      const char* kg = kfb + (long)kt * KFTB;
#pragma unroll
      for (int i = 0; i < 2; ++i) {
        int c = w * 2 + i;
        gll16(kg + c * 1024 + lane * 16, &Ks[c * 1024]);
      }
      const unsigned short* vg = vfb + (long)kt * VFT;
#pragma unroll
      for (int i = 0; i < 5; ++i) {
        int c = w + 4 * i;
        gll16(vg + c * 512 + lane * 8, &Vs[c * 512]);
      }
    }
    __syncthreads();    // gll complete (compiler drains vmcnt before barrier)
#pragma unroll
    for (int cf = 0; cf < 4; ++cf) {
      int4v k0 = *(const int4v*)&Ks[(cf * 2 + 0) * 1024 + lane * 16];
      int4v k1 = *(const int4v*)&Ks[(cf * 2 + 1) * 1024 + lane * 16];
      short4v Pp[3], Pr[3];
#pragma unroll
      for (int qs = 0; qs < 3; ++qs) {
        int4v a = int4v{0, 0, 0, 0};
        a = MFMAI8(k0, qa[qs], a);
        a = MFMAI8(k1, qb[qs], a);
        // P for q=l15, k=cf*16+l4*4+j : quantize + truncation bf16 split, in-register
        unsigned phb[4], rsb[4];
#pragma unroll
        for (int j = 0; j < 4; ++j) {
          float n = rintf((float)a[j] * c0);
          float nn = rintf(fexp2(fmaf(n, c1e, dexp[qs])));  // = rint(exp(z-m)/l/sp)
          unsigned ub = __float_as_uint(nn);
          unsigned hb = ub & 0xFFFF0000u;                  // trunc-bf16 bits
          float rsf = nn - __uint_as_float(hb);            // in [0,127], exact bf16
          phb[j] = hb >> 16;
          rsb[j] = __float_as_uint(rsf) >> 16;
        }
        Pp[qs] = pack4(phb[0], phb[1], phb[2], phb[3]);
        Pr[qs] = pack4(rsb[0], rsb[1], rsb[2], rsb[3]);
      }
#pragma unroll
      for (int dt = 0; dt < 5; ++dt) {
        short8 vv = *(const short8*)&Vs[(dt * 4 + cf) * 512 + lane * 8];
        short4v vh = __builtin_shufflevector(vv, vv, 0, 1, 2, 3);
        short4v vl = __builtin_shufflevector(vv, vv, 4, 5, 6, 7);
#pragma unroll
        for (int qs = 0; qs < 3; ++qs) {
          acc[qs][dt] = MFMA16(Pp[qs], vh, acc[qs][dt]);
          acc[qs][dt] = MFMA16(Pp[qs], vl, acc[qs][dt]);
          acc[qs][dt] = MFMA16(Pr[qs], vh, acc[qs][dt]);   // res@vl dropped (rel err ~2^-23)
        }
      }
    }
  }
  float lmax = 0.f;
#pragma unroll
  for (int qs = 0; qs < 3; ++qs)
#pragma unroll
    for (int dt = 0; dt < 5; ++dt) {
      int d = dt * 16 + l15;
#pragma unroll
      for (int j = 0; j < 4; ++j) {
        int qr = (qp * 3 + qs) * 64 + w * 16 + l4 * 4 + j;
        if (qr < Sd && d < HDd) {
          float v = sp * acc[qs][dt][j];
          O[((long)(b * Sd + qr)) * Hdim + h * HDd + d] = v;
          lmax = fmaxf(lmax, fabsf(v));
        }
      }
    }
  for (int off = 32; off; off >>= 1) lmax = fmaxf(lmax, __shfl_xor(lmax, off, 64));
  if ((tid & 63) == 0) red[w] = lmax;
  __syncthreads();
  if (tid == 0)
    atomicMaxF(&slots[SL_O], fmaxf(fmaxf(red[0], red[1]), fmaxf(red[2], red[3])));
}

// ---------------- host ----------------
extern "C" void kernel_launch(void* const* d_in, const int* in_sizes, int n_in,
                              void* d_out, int out_size, void* d_ws, size_t ws_size,
                              hipStream_t stream) {
  const float* Xin = (const float*)d_in[0];
  const float* Wq = (const float*)d_in[1];
  const float* bq = (const float*)d_in[2];
  const float* Wk = (const float*)d_in[3];
  const float* bk = (const float*)d_in[4];
  const float* Wv = (const float*)d_in[5];
  const float* bv = (const float*)d_in[6];
  const float* Wo = (const float*)d_in[7];
  const float* bo = (const float*)d_in[8];
  float* out = (float*)d_out;
  char* ws = (char*)d_ws;

  size_t off = 0;
  auto alloc = [&](size_t bytes) {
    void* p = ws + off;
    off = (off + bytes + 255) & ~(size_t)255;
    return p;
  };
  float* slots = (float*)alloc(256);
  char* Xq  = (char*)alloc((size_t)Ntok * Hdim);
  char* Wqq = (char*)alloc((size_t)Hdim * Hdim);
  char* Wkq = (char*)alloc((size_t)Hdim * Hdim);
  char* Wvq = (char*)alloc((size_t)Hdim * Hdim);
  char* Woq = (char*)alloc((size_t)Hdim * Hdim);
  float* Kf = (float*)alloc((size_t)Ntok * Hdim * 4);
  float* Vf = (float*)alloc((size_t)Ntok * Hdim * 4);
  char* Qq = (char*)alloc((size_t)Ntok * Hdim);
  char* KFr = (char*)alloc((size_t)BHd * 12 * KFTB);
  unsigned short* VFr = (unsigned short*)alloc((size_t)BHd * 12 * VFT * 2);
  float* m_arr = (float*)alloc((size_t)BHd * Sd * 4);
  float* l_arr = (float*)alloc((size_t)BHd * Sd * 4);
  // Aliases (lifetimes disjoint): Q f32 and O f32 live in d_out
  // (Qq extracted before attnC overwrites); Oq over Vf (dead after k_prep).
  char* Oq = (char*)Vf;
  float* Qf = out;
  float* Of = out;

  k_init<<<1, 64, 0, stream>>>(slots);
  k_absmax<<<dim3(256, 5), 256, 0, stream>>>(Xin, Wq, Wk, Wv, Wo, slots);
  k_quantXW<<<dim3(1024, 1, 2), 256, 0, stream>>>(Xin, Wq, Wk, Wv, Wo,
                                                  (unsigned int*)Xq, (unsigned int*)Wqq,
                                                  (unsigned int*)Wkq, (unsigned int*)Wvq,
                                                  (unsigned int*)Woq, slots);

  k_gemm3<<<dim3(92, 27), 256, 0, stream>>>(Xq, Wqq, Wkq, Wvq, bq, bk, bv,
                                            Qf, Kf, Vf, slots);

  k_prep<<<dim3(12, 256, 3), 256, 0, stream>>>(Qf, (unsigned int*)Qq, Kf, KFr, Vf, VFr, slots);

  k_attnA<<<dim3(4, 256), 256, 0, stream>>>(Qq, KFr, slots);
  k_attnB<<<dim3(4, 256), 256, 0, stream>>>(Qq, KFr, slots, m_arr, l_arr);
  k_attnC<<<dim3(4, 256), 256, 0, stream>>>(Qq, KFr, VFr, m_arr, l_arr, slots, Of);

  k_quant8i<<<1024, 256, 0, stream>>>(Of, (unsigned int*)Oq, (long)Ntok * Hdim, slots, SL_O);
  k_gemm<<<dim3(92, 9), 256, 0, stream>>>(Oq, Woq, bo, out, slots, SL_O, SL_WO, -1);
}

// Round 14
// 436.288 us; speedup vs baseline: 1.0570x; 1.0570x over previous
//
#include <hip/hip_runtime.h>
#include <math.h>

// Problem constants
#define Hdim 1152
#define NHd  16
#define HDd  72
#define Bd   16
#define Sd   729
#define Ntok (Bd*Sd)      // 11664
#define BHd  (Bd*NHd)     // 256
#define SCALE_F 0.117851130197757934f  // 72^-0.5
#define LOG2E 1.44269504088896340736f

// Fragment-tile sizes
#define KFTB 8192    // bytes per (bh,kt): 8 chunks * 1024 (i8, K=64 layout)
#define VFT 10240    // ushorts per (bh,kt): 20 chunks * 512 (bf16 hi/lo interleaved)

// scalar slots in ws
#define SL_X 0
#define SL_WQ 1
#define SL_WK 2
#define SL_WV 3
#define SL_WO 4
#define SL_Q 5
#define SL_K 6
#define SL_LOGIT 8
#define SL_LMIN 9
#define SL_O 10

typedef short short8 __attribute__((ext_vector_type(8)));
typedef short short4v __attribute__((ext_vector_type(4)));
typedef float f32x4 __attribute__((ext_vector_type(4)));
typedef int int4v __attribute__((ext_vector_type(4)));

static __device__ __forceinline__ unsigned short f2bf(float f) {
  unsigned b = __float_as_uint(f);
  return (unsigned short)((b + 0x7FFFu + ((b >> 16) & 1u)) >> 16);  // RNE
}
static __device__ __forceinline__ float bf2f(unsigned short u) {
  return __uint_as_float(((unsigned)u) << 16);
}
static __device__ __forceinline__ void atomicMaxF(float* p, float v) {
  atomicMax((unsigned int*)p, __float_as_uint(v));   // v >= 0 only
}
static __device__ __forceinline__ void atomicMinF(float* p, float v) {
  atomicMin((unsigned int*)p, __float_as_uint(v));   // v > 0 only
}
static __device__ __forceinline__ float qscale(float mx, float qmax) {
  return fmaxf(mx, 1e-8f) / qmax;
}
static __device__ __forceinline__ float fexp2(float x) {
  float r; asm("v_exp_f32 %0, %1" : "=v"(r) : "v"(x)); return r;
}
static __device__ __forceinline__ float flog2(float x) {
  float r; asm("v_log_f32 %0, %1" : "=v"(r) : "v"(x)); return r;
}
static __device__ __forceinline__ short4v pack4(unsigned a, unsigned b, unsigned c, unsigned d) {
  union { unsigned u[2]; short4v s; } t;
  t.u[0] = a | (b << 16);
  t.u[1] = c | (d << 16);
  return t.s;
}
static __device__ __forceinline__ int q8i(float v, float s) {
  return (int)fminf(fmaxf(rintf(v / s), -128.f), 127.f);
}

#if __has_builtin(__builtin_amdgcn_mfma_f32_16x16x16bf16_1k)
#define MFMA16(a, b, c) __builtin_amdgcn_mfma_f32_16x16x16bf16_1k(a, b, c, 0, 0, 0)
#else
static __device__ __forceinline__ f32x4 MFMA16(short4v a, short4v b, f32x4 c) {
  asm("v_mfma_f32_16x16x16_bf16 %0, %1, %2, %0" : "+v"(c) : "v"(a), "v"(b));
  return c;
}
#endif
#if __has_builtin(__builtin_amdgcn_mfma_i32_16x16x64_i8)
#define MFMAI8(a, b, c) __builtin_amdgcn_mfma_i32_16x16x64_i8(a, b, c, 0, 0, 0)
#else
static __device__ __forceinline__ int4v MFMAI8(int4v a, int4v b, int4v c) {
  asm("v_mfma_i32_16x16x64_i8 %0, %1, %2, %0" : "+v"(c) : "v"(a), "v"(b));
  return c;
}
#endif

static __device__ __forceinline__ void gll16(const void* g, void* l) {
  __builtin_amdgcn_global_load_lds((const __attribute__((address_space(1))) void*)g,
                                   (__attribute__((address_space(3))) void*)l, 16, 0, 0);
}

// ---------------- init ----------------
__global__ void k_init(float* slots) {
  int i = threadIdx.x;
  if (i < 32) slots[i] = (i == SL_LMIN) ? __builtin_inff() : 0.0f;
}

// ---------------- abs-max over X and the 4 weights ----------------
__launch_bounds__(256)
__global__ void k_absmax(const float* __restrict__ X, const float* __restrict__ W0,
                         const float* __restrict__ W1, const float* __restrict__ W2,
                         const float* __restrict__ W3, float* slots) {
  int seg = blockIdx.y;
  const float* p; long n; int slot;
  if (seg == 0) { p = X; n = (long)Ntok * Hdim; slot = SL_X; }
  else {
    const float* ws4[4] = {W0, W1, W2, W3};
    p = ws4[seg - 1]; n = (long)Hdim * Hdim; slot = SL_WQ + seg - 1;
  }
  long n4 = n >> 2;
  const float4* p4 = (const float4*)p;
  float m = 0.f;
  for (long i = (long)blockIdx.x * blockDim.x + threadIdx.x; i < n4;
       i += (long)gridDim.x * blockDim.x) {
    float4 v = p4[i];
    m = fmaxf(m, fmaxf(fmaxf(fabsf(v.x), fabsf(v.y)), fmaxf(fabsf(v.z), fabsf(v.w))));
  }
  for (int off = 32; off; off >>= 1) m = fmaxf(m, __shfl_xor(m, off, 64));
  __shared__ float red[4];
  if ((threadIdx.x & 63) == 0) red[threadIdx.x >> 6] = m;
  __syncthreads();
  if (threadIdx.x == 0)
    atomicMaxF(&slots[slot], fmaxf(fmaxf(red[0], red[1]), fmaxf(red[2], red[3])));
}

// ---------------- 8-bit fake-quant helper body ----------------
static __device__ __forceinline__ void quant_body(const float* __restrict__ in,
                                                  unsigned int* __restrict__ out,
                                                  long n4, float s, long start, long stride) {
  const float4* in4 = (const float4*)in;
  for (long i = start; i < n4; i += stride) {
    float4 v = in4[i];
    unsigned a = (unsigned)q8i(v.x, s) & 255u;
    unsigned b = (unsigned)q8i(v.y, s) & 255u;
    unsigned c = (unsigned)q8i(v.z, s) & 255u;
    unsigned d = (unsigned)q8i(v.w, s) & 255u;
    out[i] = a | (b << 8) | (c << 16) | (d << 24);
  }
}

// f32 -> i8 (standalone, for O)
__launch_bounds__(256)
__global__ void k_quant8i(const float* __restrict__ in, unsigned int* __restrict__ out,
                          long n, const float* __restrict__ slots, int slot) {
  float s = qscale(slots[slot], 127.0f);
  quant_body(in, out, n >> 2, s,
             (long)blockIdx.x * blockDim.x + threadIdx.x,
             (long)gridDim.x * blockDim.x);
}

// fused X + 4 weights quant: grid (1024, 1, 2)
__launch_bounds__(256)
__global__ void k_quantXW(const float* __restrict__ X, const float* __restrict__ W0,
                          const float* __restrict__ W1, const float* __restrict__ W2,
                          const float* __restrict__ W3,
                          unsigned int* OX, unsigned int* O0, unsigned int* O1,
                          unsigned int* O2, unsigned int* O3,
                          const float* __restrict__ slots) {
  if (blockIdx.z == 0) {
    float s = qscale(slots[SL_X], 127.0f);
    quant_body(X, OX, ((long)Ntok * Hdim) >> 2, s,
               (long)blockIdx.x * blockDim.x + threadIdx.x,
               (long)gridDim.x * blockDim.x);
  } else {
    int seg = blockIdx.x & 3;
    const float* ws4[4] = {W0, W1, W2, W3};
    unsigned int* os4[4] = {O0, O1, O2, O3};
    float s = qscale(slots[SL_WQ + seg], 127.0f);
    quant_body(ws4[seg], os4[seg], ((long)Hdim * Hdim) >> 2, s,
               (long)(blockIdx.x >> 2) * blockDim.x + threadIdx.x,
               (long)(gridDim.x >> 2) * blockDim.x);
  }
}

// ---------------- i8 GEMM core: dbuf LDS + counted vmcnt, swizzled reads ----------------
#define GBM 128
#define GBN 128
static __device__ __forceinline__ void gemm_core(const char* __restrict__ A,
                                                 const char* __restrict__ Bm,
                                                 int bM, int bN, int tid,
                                                 char (*As)[GBM][64],
                                                 char (*Bs)[GBN][64],
                                                 int4v acc[4][4]) {
  int lane = tid & 63, wid = tid >> 6;
  int wm = wid >> 1, wn = wid & 1;
  int l15 = lane & 15, l4 = lane >> 4;
  int srow = lane >> 2;
  int scol = ((lane & 3) ^ ((lane >> 3) & 3)) * 16;   // inverse-swizzled source col
  const char* pa = A + ((long)(bM * GBM + wid * 32) + srow) * Hdim + scol;
  const char* pb = Bm + ((long)(bN * GBN + wid * 32) + srow) * Hdim + scol;
  int csw = (l4 ^ ((l15 >> 1) & 3)) * 16;             // swizzled read chunk offset

  auto stage = [&](int buf, int kt) {
    int kb = kt * 64;
    gll16(pa + kb, &As[buf][wid * 32][0]);
    gll16(pa + kb + 16 * Hdim, &As[buf][wid * 32 + 16][0]);
    gll16(pb + kb, &Bs[buf][wid * 32][0]);
    gll16(pb + kb + 16 * Hdim, &Bs[buf][wid * 32 + 16][0]);
  };

  stage(0, 0);
#pragma unroll 1
  for (int kt = 0; kt < 18; ++kt) {
    int cur = kt & 1;
    if (kt < 17) {
      stage(cur ^ 1, kt + 1);
      asm volatile("s_waitcnt vmcnt(4)" ::: "memory");  // kt's 4 glls done; kt+1's in flight
    } else {
      asm volatile("s_waitcnt vmcnt(0)" ::: "memory");
    }
    asm volatile("s_barrier" ::: "memory");
    int4v af[4], bf4[4];
#pragma unroll
    for (int rf = 0; rf < 4; ++rf)
      af[rf] = *(const int4v*)&As[cur][wm * 64 + rf * 16 + l15][csw];
#pragma unroll
    for (int cf = 0; cf < 4; ++cf)
      bf4[cf] = *(const int4v*)&Bs[cur][wn * 64 + cf * 16 + l15][csw];
#pragma unroll
    for (int rf = 0; rf < 4; ++rf)
#pragma unroll
      for (int cf = 0; cf < 4; ++cf)
        acc[rf][cf] = MFMAI8(af[rf], bf4[cf], acc[rf][cf]);
    asm volatile("s_barrier" ::: "memory");   // reads of buf[cur] done before restage
  }
}

__launch_bounds__(256, 4)
__global__ void k_gemm(const char* __restrict__ A,
                       const char* __restrict__ Bm,
                       const float* __restrict__ bias,
                       float* __restrict__ C,
                       float* slots, int slotA, int slotB, int slotOut) {
  __shared__ char As[2][GBM][64];
  __shared__ char Bs[2][GBN][64];
  __shared__ float red[4];
  int tid = threadIdx.x, lane = tid & 63, wid = tid >> 6;
  int wm = wid >> 1, wn = wid & 1;
  int l15 = lane & 15, l4 = lane >> 4;
  int bM = blockIdx.x, bN = blockIdx.y;
  int4v acc[4][4];
  for (int rf = 0; rf < 4; ++rf)
    for (int cf = 0; cf < 4; ++cf) acc[rf][cf] = int4v{0, 0, 0, 0};
  gemm_core(A, Bm, bM, bN, tid, As, Bs, acc);
  float alpha = qscale(slots[slotA], 127.f) * qscale(slots[slotB], 127.f);
  float lmax = 0.f;
#pragma unroll
  for (int cf = 0; cf < 4; ++cf) {
    int col = bN * GBN + wn * 64 + cf * 16 + l15;
    float bv = bias[col];
#pragma unroll
    for (int rf = 0; rf < 4; ++rf)
#pragma unroll
      for (int j = 0; j < 4; ++j) {
        int row = bM * GBM + wm * 64 + rf * 16 + l4 * 4 + j;
        if (row < Ntok) {
          float v = (float)acc[rf][cf][j] * alpha + bv;
          C[(long)row * Hdim + col] = v;
          lmax = fmaxf(lmax, fabsf(v));
        }
      }
  }
  if (slotOut >= 0) {
    for (int off = 32; off; off >>= 1) lmax = fmaxf(lmax, __shfl_xor(lmax, off, 64));
    if ((tid & 63) == 0) red[wid] = lmax;
    __syncthreads();
    if (tid == 0)
      atomicMaxF(&slots[slotOut], fmaxf(fmaxf(red[0], red[1]), fmaxf(red[2], red[3])));
  }
}

// ---------------- fused QKV i8 GEMM ----------------
__launch_bounds__(256, 4)
__global__ void k_gemm3(const char* __restrict__ A,
                        const char* __restrict__ W0,
                        const char* __restrict__ W1,
                        const char* __restrict__ W2,
                        const float* __restrict__ b0, const float* __restrict__ b1,
                        const float* __restrict__ b2,
                        float* __restrict__ C0, float* __restrict__ C1,
                        float* __restrict__ C2, float* slots) {
  __shared__ char As[2][GBM][64];
  __shared__ char Bs[2][GBN][64];
  __shared__ float red[4];
  int bNg = blockIdx.y;                       // 0..26
  int mi = bNg / 9, bN = bNg - mi * 9;
  const char* Bm = mi == 0 ? W0 : (mi == 1 ? W1 : W2);
  const float* bias = mi == 0 ? b0 : (mi == 1 ? b1 : b2);
  float* C = mi == 0 ? C0 : (mi == 1 ? C1 : C2);
  int slotB = SL_WQ + mi;
  int slotOut = mi == 0 ? SL_Q : (mi == 1 ? SL_K : -1);

  int tid = threadIdx.x, lane = tid & 63, wid = tid >> 6;
  int wm = wid >> 1, wn = wid & 1;
  int l15 = lane & 15, l4 = lane >> 4;
  int bM = blockIdx.x;
  int4v acc[4][4];
  for (int rf = 0; rf < 4; ++rf)
    for (int cf = 0; cf < 4; ++cf) acc[rf][cf] = int4v{0, 0, 0, 0};
  gemm_core(A, Bm, bM, bN, tid, As, Bs, acc);
  float alpha = qscale(slots[SL_X], 127.f) * qscale(slots[slotB], 127.f);
  float lmax = 0.f;
#pragma unroll
  for (int cf = 0; cf < 4; ++cf) {
    int col = bN * GBN + wn * 64 + cf * 16 + l15;
    float bv = bias[col];
#pragma unroll
    for (int rf = 0; rf < 4; ++rf)
#pragma unroll
      for (int j = 0; j < 4; ++j) {
        int row = bM * GBM + wm * 64 + rf * 16 + l4 * 4 + j;
        if (row < Ntok) {
          float v = (float)acc[rf][cf][j] * alpha + bv;
          C[(long)row * Hdim + col] = v;
          lmax = fmaxf(lmax, fabsf(v));
        }
      }
  }
  if (slotOut >= 0) {
    for (int off = 32; off; off >>= 1) lmax = fmaxf(lmax, __shfl_xor(lmax, off, 64));
    if ((tid & 63) == 0) red[wid] = lmax;
    __syncthreads();
    if (tid == 0)
      atomicMaxF(&slots[slotOut], fmaxf(fmaxf(red[0], red[1]), fmaxf(red[2], red[3])));
  }
}

// ---------------- fused prep: z=0 Q-quant, z=1 K-frag, z=2 V-split ----------------
// grid (12, 256, 3)
__launch_bounds__(256)
__global__ void k_prep(const float* __restrict__ Qf, unsigned int* __restrict__ Qq,
                       const float* __restrict__ Kf, char* __restrict__ KF,
                       const float* __restrict__ Vf, unsigned short* __restrict__ VF,
                       const float* __restrict__ slots) {
  int kt = blockIdx.x, bh = blockIdx.y;
  int b = bh >> 4, h = bh & 15;
  int tid = threadIdx.x, lane = tid & 63, w = tid >> 6;
  int l15 = lane & 15, l4 = lane >> 4;
  if (blockIdx.z == 0) {
    float s = qscale(slots[SL_Q], 127.0f);
    quant_body(Qf, Qq, ((long)Ntok * Hdim) >> 2, s,
               (long)(bh * 12 + kt) * 256 + tid, (long)12 * 256 * 256);
  } else if (blockIdx.z == 1) {
    float s = qscale(slots[SL_K], 127.0f);
    long obase = ((long)(bh * 12 + kt)) * KFTB;
#pragma unroll
    for (int i = 0; i < 2; ++i) {
      int p = w * 2 + i;
      int cf = p >> 1, c = p & 1;
      int token = kt * 64 + cf * 16 + l15;
      char ov[16];
#pragma unroll
      for (int j = 0; j < 16; ++j) ov[j] = 0;
      if (token < Sd) {
        const float* src = &Kf[((long)(b * Sd + token)) * Hdim + h * HDd];
        if (c == 0) {
#pragma unroll
          for (int j = 0; j < 16; ++j) ov[j] = (char)q8i(src[l4 * 16 + j], s);
        } else if (l4 == 0) {
#pragma unroll
          for (int j = 0; j < 8; ++j) ov[j] = (char)q8i(src[64 + j], s);
        }
      }
      *(int4v*)&KF[obase + p * 1024 + lane * 16] = *(int4v*)ov;
    }
  } else {
    long obase = ((long)(bh * 12 + kt)) * VFT;
#pragma unroll
    for (int i = 0; i < 5; ++i) {
      int p = w + 4 * i;            // p = dt*4 + cf
      int dt = p >> 2, cf = p & 3;
      int d = dt * 16 + l15;
      int tok0 = kt * 64 + cf * 16 + l4 * 4;
      unsigned short u[8];
#pragma unroll
      for (int j = 0; j < 4; ++j) {
        int tok = tok0 + j;
        float v = 0.f;
        if (tok < Sd && d < HDd)
          v = Vf[((long)(b * Sd + tok)) * Hdim + h * HDd + d];
        unsigned short hb = f2bf(v);
        u[j] = hb;
        u[4 + j] = f2bf(v - bf2f(hb));
      }
      *(short8*)&VF[obase + (long)p * 512 + lane * 8] = *(short8*)u;
    }
  }
}

// per-lane i8 Q fragments straight from global (B operand: q col = l15, K-grp = l4)
static __device__ __forceinline__ void loadQ8(const char* __restrict__ Qq,
                                              int b, int h, int qc, int l4,
                                              int4v& qa, int4v& qb) {
  const char* qp = &Qq[((long)(b * Sd + qc)) * Hdim + h * HDd];
  union { long l[2]; int4v v; } u0, u1;
  u0.l[0] = *(const long*)(qp + l4 * 16);
  u0.l[1] = *(const long*)(qp + l4 * 16 + 8);
  qa = u0.v;
  u1.l[0] = (l4 == 0) ? *(const long*)(qp + 64) : 0L;
  u1.l[1] = 0L;
  qb = u1.v;
}

// ---------------- attn pass A: global max |logit| ----------------
// grid (4, 256): 3 q-tiles per block; K frags in registers, no LDS/barriers.
__launch_bounds__(256, 4)
__global__ void k_attnA(const char* __restrict__ Qq,
                        const char* __restrict__ KF, float* slots) {
  __shared__ float red[4];
  int qh = blockIdx.x, bh = blockIdx.y;
  int b = bh >> 4, h = bh & 15;
  int tid = threadIdx.x, lane = tid & 63, w = tid >> 6;
  int l15 = lane & 15, l4 = lane >> 4;
  const char* kfb = KF + (long)bh * 12 * KFTB;
  int4v qa[3], qb[3];
#pragma unroll
  for (int qs = 0; qs < 3; ++qs) {
    int qrow = (qh * 3 + qs) * 64 + w * 16 + l15;
    int qc = qrow > Sd - 1 ? Sd - 1 : qrow;
    loadQ8(Qq, b, h, qc, l4, qa[qs], qb[qs]);
  }
  float mx = 0.f;
#pragma unroll 1
  for (int kt = 0; kt < 12; ++kt) {
    int4v kf[8];
#pragma unroll
    for (int p = 0; p < 8; ++p)
      kf[p] = *(const int4v*)&kfb[(long)kt * KFTB + p * 1024 + lane * 16];
#pragma unroll
    for (int qs = 0; qs < 3; ++qs) {
#pragma unroll
      for (int cf = 0; cf < 4; ++cf) {
        int4v a = int4v{0, 0, 0, 0};
        a = MFMAI8(kf[cf * 2 + 0], qa[qs], a);
        a = MFMAI8(kf[cf * 2 + 1], qb[qs], a);
#pragma unroll
        for (int j = 0; j < 4; ++j) mx = fmaxf(mx, fabsf((float)a[j]));
      }
    }
  }
  mx *= qscale(slots[SL_Q], 127.f) * qscale(slots[SL_K], 127.f);
  for (int off = 32; off; off >>= 1) mx = fmaxf(mx, __shfl_xor(mx, off, 64));
  if ((tid & 63) == 0) red[w] = mx;
  __syncthreads();
  if (tid == 0)
    atomicMaxF(&slots[SL_LOGIT], fmaxf(fmaxf(red[0], red[1]), fmaxf(red[2], red[3])));
}

// ---------------- attn pass B: per-row m (n-space), l ; global min l ----------------
__launch_bounds__(256, 4)
__global__ void k_attnB(const char* __restrict__ Qq,
                        const char* __restrict__ KF, float* slots,
                        float* __restrict__ m_arr, float* __restrict__ l_arr) {
  __shared__ float red[4];
  int qh = blockIdx.x, bh = blockIdx.y;
  int b = bh >> 4, h = bh & 15;
  int tid = threadIdx.x, lane = tid & 63, w = tid >> 6;
  int l15 = lane & 15, l4 = lane >> 4;
  const char* kfb = KF + (long)bh * 12 * KFTB;
  int4v qa[3], qb[3];
#pragma unroll
  for (int qs = 0; qs < 3; ++qs) {
    int qrow = (qh * 3 + qs) * 64 + w * 16 + l15;
    int qc = qrow > Sd - 1 ? Sd - 1 : qrow;
    loadQ8(Qq, b, h, qc, l4, qa[qs], qb[qs]);
  }
  float s16 = qscale(slots[SL_LOGIT], 32767.f);
  float sqk = qscale(slots[SL_Q], 127.f) * qscale(slots[SL_K], 127.f);
  float c0 = sqk / s16;                 // raw-dot -> n units
  float c1e = s16 * SCALE_F * LOG2E;    // n units -> log2 space
  float m_run[3] = {-3.0e38f, -3.0e38f, -3.0e38f};
  float l_run[3] = {0.f, 0.f, 0.f};
#pragma unroll 1
  for (int kt = 0; kt < 12; ++kt) {
    int4v kf[8];
#pragma unroll
    for (int p = 0; p < 8; ++p)
      kf[p] = *(const int4v*)&kfb[(long)kt * KFTB + p * 1024 + lane * 16];
#pragma unroll
    for (int qs = 0; qs < 3; ++qs) {
      float nv[16];
#pragma unroll
      for (int cf = 0; cf < 4; ++cf) {
        int4v a = int4v{0, 0, 0, 0};
        a = MFMAI8(kf[cf * 2 + 0], qa[qs], a);
        a = MFMAI8(kf[cf * 2 + 1], qb[qs], a);
#pragma unroll
        for (int j = 0; j < 4; ++j) nv[cf * 4 + j] = rintf((float)a[j] * c0);
      }
      if (kt == 11) {
#pragma unroll
        for (int cf = 0; cf < 4; ++cf)
#pragma unroll
          for (int j = 0; j < 4; ++j) {
            int kcol = 704 + cf * 16 + l4 * 4 + j;
            if (kcol > Sd - 1) nv[cf * 4 + j] = -3.0e30f;
          }
      }
      float mt = nv[0];
#pragma unroll
      for (int i = 1; i < 16; ++i) mt = fmaxf(mt, nv[i]);
      mt = fmaxf(mt, __shfl_xor(mt, 16, 64));
      mt = fmaxf(mt, __shfl_xor(mt, 32, 64));
      float mn = fmaxf(m_run[qs], mt);
      float f = fexp2((m_run[qs] - mn) * c1e);
      float se = 0.f;
#pragma unroll
      for (int i = 0; i < 16; ++i) se += fexp2((nv[i] - mn) * c1e);
      se += __shfl_xor(se, 16, 64);
      se += __shfl_xor(se, 32, 64);
      l_run[qs] = l_run[qs] * f + se;
      m_run[qs] = mn;
    }
  }
  float lmin = 3.0e38f;
#pragma unroll
  for (int qs = 0; qs < 3; ++qs) {
    int qrow = (qh * 3 + qs) * 64 + w * 16 + l15;
    if (qrow < Sd) {
      if (l4 == 0) {
        m_arr[bh * Sd + qrow] = m_run[qs];
        l_arr[bh * Sd + qrow] = l_run[qs];
      }
      lmin = fminf(lmin, l_run[qs]);
    }
  }
  for (int off = 32; off; off >>= 1) lmin = fminf(lmin, __shfl_xor(lmin, off, 64));
  if ((tid & 63) == 0) red[w] = lmin;
  __syncthreads();
  if (tid == 0)
    atomicMinF(&slots[SL_LMIN], fminf(fminf(red[0], red[1]), fminf(red[2], red[3])));
}

// ---------------- attn pass C: single-buf LDS staging (r12 proven), 2 q-tiles/block ----
// grid (6, 256): XCD-grouped. K (8 KB, i8) + V (20 KB, bf16) staged per kt via gll.
__launch_bounds__(256, 5)
__global__ void k_attnC(const char* __restrict__ Qq,
                        const char* __restrict__ KF,
                        const unsigned short* __restrict__ VF,
                        const float* __restrict__ m_arr, const float* __restrict__ l_arr,
                        float* slots, float* __restrict__ O) {
  __shared__ char Ks[KFTB];
  __shared__ unsigned short Vs[VFT];
  __shared__ float red[4];
  int qp, bh;
  {
    int id = blockIdx.y * 6 + blockIdx.x;   // 0..1535
    int xcd = id & 7, sub = id >> 3;        // 192 per xcd
    int bhl = sub / 6;
    qp = sub - bhl * 6;
    bh = xcd * 32 + bhl;
  }
  int b = bh >> 4, h = bh & 15;
  int tid = threadIdx.x, lane = tid & 63, w = tid >> 6;
  int l15 = lane & 15, l4 = lane >> 4;
  float s16 = qscale(slots[SL_LOGIT], 32767.f);
  float sqk = qscale(slots[SL_Q], 127.f) * qscale(slots[SL_K], 127.f);
  float c0 = sqk / s16;
  float c1e = s16 * SCALE_F * LOG2E;
  float pmaxv = 1.0f / slots[SL_LMIN];
  float sp = fmaxf(pmaxv, 1e-8f) / 32767.0f;
  float inv_sp = 1.0f / sp;
  int4v qa[2], qb[2];
  float dexp[2];      // log2(c2) - mn*c1e : folds /l, /sp, -m into the exponent
#pragma unroll
  for (int qs = 0; qs < 2; ++qs) {
    int qrow = (qp * 2 + qs) * 64 + w * 16 + l15;
    int qc = qrow > Sd - 1 ? Sd - 1 : qrow;
    loadQ8(Qq, b, h, qc, l4, qa[qs], qb[qs]);
    float mn = m_arr[bh * Sd + qc];
    float c2 = (1.0f / l_arr[bh * Sd + qc]) * inv_sp;
    dexp[qs] = flog2(c2) - mn * c1e;
  }
  const char* kfb = KF + (long)bh * 12 * KFTB;
  const unsigned short* vfb = VF + (long)bh * 12 * VFT;
  f32x4 acc[2][5];
#pragma unroll
  for (int qs = 0; qs < 2; ++qs)
#pragma unroll
    for (int i = 0; i < 5; ++i) acc[qs][i] = f32x4{0.f, 0.f, 0.f, 0.f};

#pragma unroll 1
  for (int kt = 0; kt < 12; ++kt) {
    __syncthreads();    // prior iteration's LDS reads complete
    {
      const char* kg = kfb + (long)kt * KFTB;
#pragma unroll
      for (int i = 0; i < 2; ++i) {
        int c = w * 2 + i;
        gll16(kg + c * 1024 + lane * 16, &Ks[c * 1024]);
      }
      const unsigned short* vg = vfb + (long)kt * VFT;
#pragma unroll
      for (int i = 0; i < 5; ++i) {
        int c = w + 4 * i;
        gll16(vg + c * 512 + lane * 8, &Vs[c * 512]);
      }
    }
    __syncthreads();    // gll complete (compiler drains vmcnt before barrier)
#pragma unroll
    for (int cf = 0; cf < 4; ++cf) {
      int4v k0 = *(const int4v*)&Ks[(cf * 2 + 0) * 1024 + lane * 16];
      int4v k1 = *(const int4v*)&Ks[(cf * 2 + 1) * 1024 + lane * 16];
      short4v Pp[2], Pr[2];
#pragma unroll
      for (int qs = 0; qs < 2; ++qs) {
        int4v a = int4v{0, 0, 0, 0};
        a = MFMAI8(k0, qa[qs], a);
        a = MFMAI8(k1, qb[qs], a);
        // P for q=l15, k=cf*16+l4*4+j : quantize + truncation bf16 split, in-register
        unsigned phb[4], rsb[4];
#pragma unroll
        for (int j = 0; j < 4; ++j) {
          float n = rintf((float)a[j] * c0);
          float nn = rintf(fexp2(fmaf(n, c1e, dexp[qs])));  // = rint(exp(z-m)/l/sp)
          unsigned ub = __float_as_uint(nn);
          unsigned hb = ub & 0xFFFF0000u;                  // trunc-bf16 bits
          float rsf = nn - __uint_as_float(hb);            // in [0,127], exact bf16
          phb[j] = hb >> 16;
          rsb[j] = __float_as_uint(rsf) >> 16;
        }
        Pp[qs] = pack4(phb[0], phb[1], phb[2], phb[3]);
        Pr[qs] = pack4(rsb[0], rsb[1], rsb[2], rsb[3]);
      }
#pragma unroll
      for (int dt = 0; dt < 5; ++dt) {
        short8 vv = *(const short8*)&Vs[(dt * 4 + cf) * 512 + lane * 8];
        short4v vh = __builtin_shufflevector(vv, vv, 0, 1, 2, 3);
        short4v vl = __builtin_shufflevector(vv, vv, 4, 5, 6, 7);
#pragma unroll
        for (int qs = 0; qs < 2; ++qs) {
          acc[qs][dt] = MFMA16(Pp[qs], vh, acc[qs][dt]);
          acc[qs][dt] = MFMA16(Pp[qs], vl, acc[qs][dt]);
          acc[qs][dt] = MFMA16(Pr[qs], vh, acc[qs][dt]);   // res@vl dropped (rel err ~2^-23)
        }
      }
    }
  }
  float lmax = 0.f;
#pragma unroll
  for (int qs = 0; qs < 2; ++qs)
#pragma unroll
    for (int dt = 0; dt < 5; ++dt) {
      int d = dt * 16 + l15;
#pragma unroll
      for (int j = 0; j < 4; ++j) {
        int qr = (qp * 2 + qs) * 64 + w * 16 + l4 * 4 + j;
        if (qr < Sd && d < HDd) {
          float v = sp * acc[qs][dt][j];
          O[((long)(b * Sd + qr)) * Hdim + h * HDd + d] = v;
          lmax = fmaxf(lmax, fabsf(v));
        }
      }
    }
  for (int off = 32; off; off >>= 1) lmax = fmaxf(lmax, __shfl_xor(lmax, off, 64));
  if ((tid & 63) == 0) red[w] = lmax;
  __syncthreads();
  if (tid == 0)
    atomicMaxF(&slots[SL_O], fmaxf(fmaxf(red[0], red[1]), fmaxf(red[2], red[3])));
}

// ---------------- host ----------------
extern "C" void kernel_launch(void* const* d_in, const int* in_sizes, int n_in,
                              void* d_out, int out_size, void* d_ws, size_t ws_size,
                              hipStream_t stream) {
  const float* Xin = (const float*)d_in[0];
  const float* Wq = (const float*)d_in[1];
  const float* bq = (const float*)d_in[2];
  const float* Wk = (const float*)d_in[3];
  const float* bk = (const float*)d_in[4];
  const float* Wv = (const float*)d_in[5];
  const float* bv = (const float*)d_in[6];
  const float* Wo = (const float*)d_in[7];
  const float* bo = (const float*)d_in[8];
  float* out = (float*)d_out;
  char* ws = (char*)d_ws;

  size_t off = 0;
  auto alloc = [&](size_t bytes) {
    void* p = ws + off;
    off = (off + bytes + 255) & ~(size_t)255;
    return p;
  };
  float* slots = (float*)alloc(256);
  char* Xq  = (char*)alloc((size_t)Ntok * Hdim);
  char* Wqq = (char*)alloc((size_t)Hdim * Hdim);
  char* Wkq = (char*)alloc((size_t)Hdim * Hdim);
  char* Wvq = (char*)alloc((size_t)Hdim * Hdim);
  char* Woq = (char*)alloc((size_t)Hdim * Hdim);
  float* Kf = (float*)alloc((size_t)Ntok * Hdim * 4);
  float* Vf = (float*)alloc((size_t)Ntok * Hdim * 4);
  char* Qq = (char*)alloc((size_t)Ntok * Hdim);
  char* KFr = (char*)alloc((size_t)BHd * 12 * KFTB);
  unsigned short* VFr = (unsigned short*)alloc((size_t)BHd * 12 * VFT * 2);
  float* m_arr = (float*)alloc((size_t)BHd * Sd * 4);
  float* l_arr = (float*)alloc((size_t)BHd * Sd * 4);
  // Aliases (lifetimes disjoint): Q f32 and O f32 live in d_out
  // (Qq extracted before attnC overwrites); Oq over Vf (dead after k_prep).
  char* Oq = (char*)Vf;
  float* Qf = out;
  float* Of = out;

  k_init<<<1, 64, 0, stream>>>(slots);
  k_absmax<<<dim3(256, 5), 256, 0, stream>>>(Xin, Wq, Wk, Wv, Wo, slots);
  k_quantXW<<<dim3(1024, 1, 2), 256, 0, stream>>>(Xin, Wq, Wk, Wv, Wo,
                                                  (unsigned int*)Xq, (unsigned int*)Wqq,
                                                  (unsigned int*)Wkq, (unsigned int*)Wvq,
                                                  (unsigned int*)Woq, slots);

  k_gemm3<<<dim3(92, 27), 256, 0, stream>>>(Xq, Wqq, Wkq, Wvq, bq, bk, bv,
                                            Qf, Kf, Vf, slots);

  k_prep<<<dim3(12, 256, 3), 256, 0, stream>>>(Qf, (unsigned int*)Qq, Kf, KFr, Vf, VFr, slots);

  k_attnA<<<dim3(4, 256), 256, 0, stream>>>(Qq, KFr, slots);
  k_attnB<<<dim3(4, 256), 256, 0, stream>>>(Qq, KFr, slots, m_arr, l_arr);
  k_attnC<<<dim3(6, 256), 256, 0, stream>>>(Qq, KFr, VFr, m_arr, l_arr, slots, Of);

  k_quant8i<<<1024, 256, 0, stream>>>(Of, (unsigned int*)Oq, (long)Ntok * Hdim, slots, SL_O);
  k_gemm<<<dim3(92, 9), 256, 0, stream>>>(Oq, Woq, bo, out, slots, SL_O, SL_WO, -1);
}